// Round 6
// baseline (935.313 us; speedup 1.0000x reference)
//
#include <hip/hip_runtime.h>
#include <cstdint>
#include <cstddef>

typedef unsigned short ushort_t;
typedef __attribute__((ext_vector_type(8))) __bf16 bf16x8;
typedef __attribute__((ext_vector_type(4))) float f32x4;

#define DEVINL __device__ __forceinline__

DEVINL ushort_t f2bf(float f) {
  union { __bf16 b; ushort_t u; } v;
  v.b = (__bf16)f;
  return v.u;
}
DEVINL float bf2f(ushort_t u) {
  union { unsigned u; float f; } v; v.u = ((unsigned)u) << 16;
  return v.f;
}

DEVINL float wred_sum(float x) {
#pragma unroll
  for (int o = 32; o > 0; o >>= 1) x += __shfl_xor(x, o, 64);
  return x;
}

// async global->LDS, 16B per lane (global_load_lds_dwordx4)
DEVINL void async16(ushort_t* lds, const ushort_t* g) {
  __builtin_amdgcn_global_load_lds(
      (__attribute__((address_space(1))) const unsigned int*)g,
      (__attribute__((address_space(3))) unsigned int*)lds, 16, 0, 0);
}

template <int CPR>
DEVINL int fswz(int r) {
  if constexpr (CPR == 4) return (r >> 2) & 3;
  else return r & 7;  // CPR==8
}

// ---------------- GroupNorm ----------------
__global__ __launch_bounds__(256) void gn_stats_k(const float* __restrict__ x,
                                                  float* __restrict__ stats) {
  const int bg = blockIdx.x;
  const float4* base = (const float4*)(x + ((size_t)bg << 16));
  float s = 0.f, q = 0.f;
  for (int i = threadIdx.x; i < 16384; i += 256) {
    float4 f = base[i];
    s += f.x + f.y + f.z + f.w;
    q += f.x * f.x + f.y * f.y + f.z * f.z + f.w * f.w;
  }
  s = wred_sum(s);
  q = wred_sum(q);
  __shared__ float rs[4], rq[4];
  const int lane = threadIdx.x & 63, wid = threadIdx.x >> 6;
  if (lane == 0) { rs[wid] = s; rq[wid] = q; }
  __syncthreads();
  if (threadIdx.x == 0) {
    float S = rs[0] + rs[1] + rs[2] + rs[3];
    float Q = rq[0] + rq[1] + rq[2] + rq[3];
    float mean = S * (1.f / 65536.f);
    float var = Q * (1.f / 65536.f) - mean * mean;
    stats[2 * bg] = mean;
    stats[2 * bg + 1] = rsqrtf(var + 1e-5f);
  }
}

__global__ __launch_bounds__(256) void gn_apply_k(const float* __restrict__ x,
                                                  const float* __restrict__ stats,
                                                  const float* __restrict__ gs,
                                                  const float* __restrict__ gb,
                                                  ushort_t* __restrict__ h) {
  __shared__ ushort_t tile[32][33];
  const int bid = blockIdx.x;
  const int b = bid >> 11;
  const int r = bid & 2047;
  const int ct = r >> 7, nt = r & 127;
  const int c0 = ct << 5, n0 = nt << 5;
  const int tx = threadIdx.x & 31, ty = threadIdx.x >> 5;
#pragma unroll
  for (int i = 0; i < 4; ++i) {
    const int c = c0 + ty + i * 8;
    const float mean = stats[2 * (b * 32 + (c >> 4))];
    const float rstd = stats[2 * (b * 32 + (c >> 4)) + 1];
    const float xv = x[(((size_t)b * 512 + c) << 12) + n0 + tx];
    tile[ty + i * 8][tx] = f2bf((xv - mean) * rstd * gs[c] + gb[c]);
  }
  __syncthreads();
#pragma unroll
  for (int i = 0; i < 4; ++i) {
    const int n = n0 + ty + i * 8;
    h[(((size_t)b << 12) + n) * 512 + c0 + tx] = tile[tx][ty + i * 8];
  }
}

// fp32 -> bf16 convert with per-matrix scale (sc folded into wq)
struct Ptr4 { const float* src[4]; float wsc[4]; };
__global__ __launch_bounds__(256) void cvt_all_k(Ptr4 s, ushort_t* __restrict__ dst) {
  const int i = blockIdx.x * 256 + threadIdx.x;
  const int m = i >> 18;
  dst[i] = f2bf(s.src[m][i & 262143] * s.wsc[m]);
}

// ---------------- NT GEMM (128x128, 2-barrier): C[M,N] = A[M,K] * B[N,K]^T ----
// EPI 2: fp32 transposed out + resid + bias (final projection).
// EPI 3: QKV fused, z picks weight/bias/out; z==2 (V) writes transposed [C][N].
struct Ptr3 { const float* bias[3]; ushort_t* out[3]; float bs[3]; };

template <int BM, int BN, int BK, int EPI>
__global__ __launch_bounds__(256) void gemm_nt_k(
    const ushort_t* __restrict__ A, int lda, const ushort_t* __restrict__ Bm, int ldb,
    void* __restrict__ Cout, int ldc, const float* __restrict__ bias,
    const float* __restrict__ resid, float scale, int K,
    size_t azs, size_t bzs, size_t czs, Ptr3 p3) {
  constexpr int CPR = BK / 8;
  constexpr int WTM = BM / 2, WTN = BN / 2;
  constexpr int MI = WTM / 16, NI = WTN / 16;
  constexpr int AR = (BM * CPR) / 256;
  constexpr int BR = (BN * CPR) / 256;
  __shared__ ushort_t Als[BM * BK];
  __shared__ ushort_t Bls[BN * BK];
  const int tid = threadIdx.x;
  const int lane = tid & 63;
  const int wid = tid >> 6;
  const int quad = lane >> 4;
  const int r16 = lane & 15;
  const int wm = wid >> 1, wn = wid & 1;
  const int m0 = blockIdx.y * BM;
  const int n0 = blockIdx.x * BN;
  const int zb = blockIdx.z;

  A += azs * zb;
  Bm += bzs * zb;

  f32x4 acc[MI][NI] = {};

  for (int kt = 0; kt < K; kt += BK) {
#pragma unroll
    for (int r = 0; r < AR; ++r) {
      const int s = r * 256 + tid;
      const int row = s / CPR;
      const int q = (s % CPR) ^ fswz<CPR>(row);
      async16(&Als[s << 3], A + (size_t)(m0 + row) * lda + kt + (q << 3));
    }
#pragma unroll
    for (int r = 0; r < BR; ++r) {
      const int s = r * 256 + tid;
      const int row = s / CPR;
      const int q = (s % CPR) ^ fswz<CPR>(row);
      async16(&Bls[s << 3], Bm + (size_t)(n0 + row) * ldb + kt + (q << 3));
    }
    __syncthreads();
#pragma unroll
    for (int kf = 0; kf < BK / 32; ++kf) {
      bf16x8 af[MI], bfr[NI];
#pragma unroll
      for (int mi = 0; mi < MI; ++mi) {
        const int lr = wm * WTM + mi * 16 + r16;
        const int ch = kf * 4 + quad;
        af[mi] = *reinterpret_cast<const bf16x8*>(
            &Als[(lr * CPR + (ch ^ fswz<CPR>(lr))) << 3]);
      }
#pragma unroll
      for (int ni = 0; ni < NI; ++ni) {
        const int lr = wn * WTN + ni * 16 + r16;
        const int ch = kf * 4 + quad;
        bfr[ni] = *reinterpret_cast<const bf16x8*>(
            &Bls[(lr * CPR + (ch ^ fswz<CPR>(lr))) << 3]);
      }
#pragma unroll
      for (int mi = 0; mi < MI; ++mi)
#pragma unroll
        for (int ni = 0; ni < NI; ++ni)
          acc[mi][ni] = __builtin_amdgcn_mfma_f32_16x16x32_bf16(
              af[mi], bfr[ni], acc[mi][ni], 0, 0, 0);
    }
    __syncthreads();
  }

  const int mrow = m0 + wm * WTM;
  const int ncol = n0 + wn * WTN;
  if constexpr (EPI == 2) {  // final: fp32 transposed out + resid + bias
    float* C = (float*)Cout;
#pragma unroll
    for (int ni = 0; ni < NI; ++ni) {
      const int col = ncol + ni * 16 + r16;
      const float bvv = bias[col];
#pragma unroll
      for (int mi = 0; mi < MI; ++mi) {
        const int rowb = mrow + mi * 16 + quad * 4;
        const int bb = rowb >> 12;
        const int nl = rowb & 4095;
        const size_t base = (((size_t)bb * 512 + col) << 12) + nl;
        const float4 rv = *(const float4*)&resid[base];
        float4 ov;
        ov.x = rv.x + acc[mi][ni][0] + bvv;
        ov.y = rv.y + acc[mi][ni][1] + bvv;
        ov.z = rv.z + acc[mi][ni][2] + bvv;
        ov.w = rv.w + acc[mi][ni][3] + bvv;
        *(float4*)&C[base] = ov;
      }
    }
  } else if constexpr (EPI == 3) {  // QKV, z picks weight/bias/out; z==2 V^T
    const float* bz = p3.bias[zb];
    const float bsc = p3.bs[zb];
    ushort_t* O = p3.out[zb];
    if (zb < 2) {
#pragma unroll
      for (int ni = 0; ni < NI; ++ni) {
        const int col = ncol + ni * 16 + r16;
        const float bvv = bz[col] * bsc;
#pragma unroll
        for (int mi = 0; mi < MI; ++mi) {
          const int rowb = mrow + mi * 16 + quad * 4;
#pragma unroll
          for (int rr = 0; rr < 4; ++rr)
            O[(size_t)(rowb + rr) * 512 + col] = f2bf(acc[mi][ni][rr] + bvv);
        }
      }
    } else {
#pragma unroll
      for (int ni = 0; ni < NI; ++ni) {
        const int col = ncol + ni * 16 + r16;
        const float bvv = bz[col];
#pragma unroll
        for (int mi = 0; mi < MI; ++mi) {
          const int rowb = mrow + mi * 16 + quad * 4;
          const int bb = rowb >> 12;
          const int nn = rowb & 4095;
          ushort4 pk;
          pk.x = f2bf(acc[mi][ni][0] + bvv);
          pk.y = f2bf(acc[mi][ni][1] + bvv);
          pk.z = f2bf(acc[mi][ni][2] + bvv);
          pk.w = f2bf(acc[mi][ni][3] + bvv);
          *(ushort4*)&O[(((size_t)bb * 512 + col) << 12) + nn] = pk;
        }
      }
    }
  }
}

// ------- 8-wave ONE-barrier-per-K-tile GEMM, BK=32 / 2+ blocks per CU -------
// Round-4 winning schedule, halved LDS so a co-resident block hides the
// drain/barrier/prologue/epilogue stalls. Per tile: drain lgkm+vm, single
// barrier, stage all of tile t+1 (other buffer), then an unwalled region of
// 12 ds_read_b128 + 32 MFMA the compiler pipelines with partial lgkm waits.
// EPI 4: scores -> exp(acc) bf16 store. EPI 5: PV -> acc / l (ones-MFMA l).
template <int BM, int BN, int WGM, int WGN, int EPI>
__global__ __launch_bounds__(512, 4) void gemm8o_k(
    const ushort_t* __restrict__ A, int lda,
    const ushort_t* __restrict__ Bm, int ldb,
    void* __restrict__ Cout, int ldc, int K,
    size_t azs, size_t bzs, size_t czs) {
  constexpr int WTM = BM / WGM, WTN = BN / WGN;
  constexpr int MI = WTM / 16, NI = WTN / 16;
  constexpr int MH = MI / 2;
  constexpr int ALD = BM / 128, BLD = BN / 128, TOT = ALD + BLD;
  constexpr int AHALF = BM * 32;      // ushorts per A buffer (BK=32)
  constexpr int HALF = (BM + BN) * 32;

  extern __shared__ ushort_t lds8[];
  const int tid = threadIdx.x;
  const int lane = tid & 63;
  const int quad = lane >> 4;
  const int r16 = lane & 15;
  const int wid = tid >> 6;
  const int wm = wid / WGN, wn = wid % WGN;

  // XCD-clustered block swizzle (HW runs flat%8 on XCD flat%8)
  int bx, by, bz;
  {
    const int flat = blockIdx.x + (EPI == 4 ? 16 : 4) * (blockIdx.y + 16 * blockIdx.z);
    if constexpr (EPI == 4) {  // grid 16x16x4: 4x4 tile-chunks per XCD
      const int xcd = flat & 7, s = flat >> 3;
      const int w = s & 31, half = w >> 4, idx = w & 15;
      bx = (xcd & 3) * 4 + (idx & 3);
      by = ((xcd >> 2) + 2 * half) * 4 + (idx >> 2);
      bz = s >> 5;
    } else {                   // grid 4x16x4: x-siblings (shared Se panel) per XCD
      const int xcd = flat & 7, s = flat >> 3;
      bx = s & 3;
      const int yz = xcd + (s >> 2) * 8;
      by = yz & 15; bz = yz >> 4;
    }
  }
  const int m0 = by * BM, n0 = bx * BN, zb = bz;
  A += azs * zb;
  Bm += bzs * zb;
  const int NT = K >> 5;

  // per-thread stage sources + LDS dest offsets (proven CPR=4 chunk swizzle)
  const ushort_t* src[TOT];
  int dsto[TOT];
#pragma unroll
  for (int l = 0; l < TOT; ++l) {
    const bool isA = l < ALD;
    const int li = isA ? l : l - ALD;
    const int s = li * 512 + tid;
    const int row = s >> 2;             // 4 chunks of 8 ushorts per row
    const int q = (s & 3) ^ ((row >> 2) & 3);
    src[l] = (isA ? A + (size_t)(m0 + row) * lda
                  : Bm + (size_t)(n0 + row) * ldb) + (q << 3);
    dsto[l] = (isA ? 0 : AHALF) + (s << 3);
  }

  f32x4 acc[MI][NI] = {};
  f32x4 acc_l[MI] = {};
  bf16x8 ones;
  {
    union { ushort_t u; __bf16 b; } o1; o1.u = 0x3F80;  // bf16 1.0
#pragma unroll
    for (int j = 0; j < 8; ++j) ones[j] = o1.b;
  }

  // prologue: stage tile 0 into buffer 0
#pragma unroll
  for (int l = 0; l < TOT; ++l) async16(lds8 + dsto[l], src[l]);

  for (int t = 0; t < NT; ++t) {
    const int nbuf = (t + 1) & 1;
    const ushort_t* Ab = lds8 + (t & 1) * HALF;
    const ushort_t* Bb = Ab + AHALF;
    // clamped source (dummy re-stage on last tile keeps the ledger uniform)
    const int koff = ((t + 1 < NT) ? t + 1 : NT - 1) << 5;

    // gate: my reads done (lgkm) and tile-t DMAs landed (vm; issued a full
    // tile ago). Barrier globalizes both.
    asm volatile("s_waitcnt vmcnt(0) lgkmcnt(0)" ::: "memory");
    __builtin_amdgcn_s_barrier();

    // stage the whole next tile (other buffer)
#pragma unroll
    for (int l = 0; l < TOT; ++l)
      async16(lds8 + nbuf * HALF + dsto[l], src[l] + koff);

    // unwalled read+MFMA region: full B, A in halves
    bf16x8 b_[NI], a_[MH];
#pragma unroll
    for (int j = 0; j < NI; ++j) {
      const int lr = wn * WTN + j * 16 + r16;
      const int cc = quad ^ ((lr >> 2) & 3);
      b_[j] = *reinterpret_cast<const bf16x8*>(&Bb[lr * 32 + cc * 8]);
    }
#pragma unroll
    for (int h = 0; h < 2; ++h) {
#pragma unroll
      for (int i = 0; i < MH; ++i) {
        const int lr = wm * WTM + (h * MH + i) * 16 + r16;
        const int cc = quad ^ ((lr >> 2) & 3);
        a_[i] = *reinterpret_cast<const bf16x8*>(&Ab[lr * 32 + cc * 8]);
      }
      __builtin_amdgcn_s_setprio(1);
#pragma unroll
      for (int i = 0; i < MH; ++i)
#pragma unroll
        for (int j = 0; j < NI; ++j)
          acc[h * MH + i][j] = __builtin_amdgcn_mfma_f32_16x16x32_bf16(
              a_[i], b_[j], acc[h * MH + i][j], 0, 0, 0);
      if constexpr (EPI == 5) {
#pragma unroll
        for (int i = 0; i < MH; ++i)
          acc_l[h * MH + i] = __builtin_amdgcn_mfma_f32_16x16x32_bf16(
              a_[i], ones, acc_l[h * MH + i], 0, 0, 0);
      }
      __builtin_amdgcn_s_setprio(0);
    }
  }
  // drain trailing dummy-stage DMAs before block retires
  asm volatile("s_waitcnt vmcnt(0)" ::: "memory");

  const int mrow = m0 + wm * WTM;
  const int ncol = n0 + wn * WTN;
  if constexpr (EPI == 4) {  // scores: exp + bf16 store, no reduce
    ushort_t* C = (ushort_t*)Cout + czs * zb;
#pragma unroll
    for (int mi = 0; mi < MI; ++mi) {
#pragma unroll
      for (int rr = 0; rr < 4; ++rr) {
        const int row = mrow + mi * 16 + quad * 4 + rr;
#pragma unroll
        for (int ni = 0; ni < NI; ++ni) {
          const int col = ncol + ni * 16 + r16;
          C[(size_t)row * ldc + col] = f2bf(__expf(acc[mi][ni][rr]));
        }
      }
    }
  } else {  // EPI == 5: PV, divide by in-register row sum, bf16 out
    ushort_t* C = (ushort_t*)Cout + czs * zb;
#pragma unroll
    for (int mi = 0; mi < MI; ++mi) {
#pragma unroll
      for (int rr = 0; rr < 4; ++rr) {
        const int row = mrow + mi * 16 + quad * 4 + rr;
        const float inv = 1.f / acc_l[mi][rr];
#pragma unroll
        for (int ni = 0; ni < NI; ++ni) {
          const int col = ncol + ni * 16 + r16;
          C[(size_t)row * ldc + col] = f2bf(acc[mi][ni][rr] * inv);
        }
      }
    }
  }
}

extern "C" void kernel_launch(void* const* d_in, const int* in_sizes, int n_in,
                              void* d_out, int out_size, void* d_ws, size_t ws_size,
                              hipStream_t stream) {
  const float* x  = (const float*)d_in[0];
  const float* gs = (const float*)d_in[1];
  const float* gb = (const float*)d_in[2];
  const float* wq = (const float*)d_in[3];
  const float* bq = (const float*)d_in[4];
  const float* wk = (const float*)d_in[5];
  const float* bk = (const float*)d_in[6];
  const float* wv = (const float*)d_in[7];
  const float* bv = (const float*)d_in[8];
  const float* wo = (const float*)d_in[9];
  const float* bo = (const float*)d_in[10];
  float* out = (float*)d_out;

  const size_t HNC = (size_t)4 * 4096 * 512;
  char* w = (char*)d_ws;
  float* stats  = (float*)w;    w += 4096;
  ushort_t* wb  = (ushort_t*)w; w += (size_t)4 * 262144 * 2;
  ushort_t* h   = (ushort_t*)w; w += HNC * 2;  // GN out; reused as O
  ushort_t* q   = (ushort_t*)w; w += HNC * 2;
  ushort_t* kk  = (ushort_t*)w; w += HNC * 2;
  ushort_t* vt  = (ushort_t*)w; w += HNC * 2;  // V transposed [B,C,N]
  ushort_t* Se  = (ushort_t*)w; w += (size_t)4 * 4096 * 4096 * 2;  // exp(S) bf16

  const float sc = 0.044194173824159216f;  // 512^-0.5, folded into wq/bq

  static bool attr_done = false;
  if (!attr_done) {
    (void)hipFuncSetAttribute((const void*)gemm8o_k<256, 256, 2, 4, 4>,
                              hipFuncAttributeMaxDynamicSharedMemorySize, 65536);
    (void)hipFuncSetAttribute((const void*)gemm8o_k<256, 128, 4, 2, 5>,
                              hipFuncAttributeMaxDynamicSharedMemorySize, 49152);
    attr_done = true;
  }

  gn_stats_k<<<128, 256, 0, stream>>>(x, stats);
  gn_apply_k<<<8192, 256, 0, stream>>>(x, stats, gs, gb, h);
  Ptr4 wsrc;
  wsrc.src[0] = wq; wsrc.src[1] = wk; wsrc.src[2] = wv; wsrc.src[3] = wo;
  wsrc.wsc[0] = sc; wsrc.wsc[1] = 1.f; wsrc.wsc[2] = 1.f; wsrc.wsc[3] = 1.f;
  cvt_all_k<<<4096, 256, 0, stream>>>(wsrc, wb);

  Ptr3 qkv;
  qkv.bias[0] = bq; qkv.bias[1] = bk; qkv.bias[2] = bv;
  qkv.out[0] = q; qkv.out[1] = kk; qkv.out[2] = vt;
  qkv.bs[0] = sc; qkv.bs[1] = 1.f; qkv.bs[2] = 1.f;
  gemm_nt_k<128, 128, 32, 3><<<dim3(4, 128, 3), 256, 0, stream>>>(
      h, 512, wb, 512, nullptr, 0, nullptr, nullptr, 1.f, 512,
      0, 262144, 0, qkv);

  // Se[z] = exp(q k^T) bf16 (one-barrier pipeline, BK=32, 2 blocks/CU)
  gemm8o_k<256, 256, 2, 4, 4><<<dim3(16, 16, 4), 512, 65536, stream>>>(
      q, 512, kk, 512, Se, 4096, 512,
      (size_t)4096 * 512, (size_t)4096 * 512, (size_t)4096 * 4096);
  // O[z] = (Se V) / l, l computed in-kernel via ones-MFMA (3 blocks/CU)
  gemm8o_k<256, 128, 4, 2, 5><<<dim3(4, 16, 4), 512, 49152, stream>>>(
      Se, 4096, vt, 4096, h, 512, 4096,
      (size_t)4096 * 4096, (size_t)512 * 4096, (size_t)4096 * 512);

  // out = x + O @ wo^T + bo, transposed back to [B,C,H,W]
  Ptr3 e0{};
  gemm_nt_k<128, 128, 32, 2><<<dim3(4, 128, 1), 256, 0, stream>>>(
      h, 512, wb + (size_t)3 * 262144, 512, out, 512, bo, x, 1.f, 512,
      0, 0, 0, e0);
}

// Round 7
// 385.527 us; speedup vs baseline: 2.4261x; 2.4261x over previous
//
#include <hip/hip_runtime.h>
#include <cstdint>
#include <cstddef>

typedef unsigned short ushort_t;
typedef __attribute__((ext_vector_type(8))) __bf16 bf16x8;
typedef __attribute__((ext_vector_type(4))) float f32x4;

#define DEVINL __device__ __forceinline__

DEVINL ushort_t f2bf(float f) {
  union { __bf16 b; ushort_t u; } v;
  v.b = (__bf16)f;
  return v.u;
}
DEVINL float bf2f(ushort_t u) {
  union { unsigned u; float f; } v; v.u = ((unsigned)u) << 16;
  return v.f;
}

DEVINL float wred_sum(float x) {
#pragma unroll
  for (int o = 32; o > 0; o >>= 1) x += __shfl_xor(x, o, 64);
  return x;
}

// async global->LDS, 16B per lane (global_load_lds_dwordx4)
DEVINL void async16(ushort_t* lds, const ushort_t* g) {
  __builtin_amdgcn_global_load_lds(
      (__attribute__((address_space(1))) const unsigned int*)g,
      (__attribute__((address_space(3))) unsigned int*)lds, 16, 0, 0);
}

template <int CPR>
DEVINL int fswz(int r) {
  if constexpr (CPR == 4) return (r >> 2) & 3;
  else return r & 7;  // CPR==8
}

// ---------------- GroupNorm ----------------
__global__ __launch_bounds__(256) void gn_stats_k(const float* __restrict__ x,
                                                  float* __restrict__ stats) {
  const int bg = blockIdx.x;
  const float4* base = (const float4*)(x + ((size_t)bg << 16));
  float s = 0.f, q = 0.f;
  for (int i = threadIdx.x; i < 16384; i += 256) {
    float4 f = base[i];
    s += f.x + f.y + f.z + f.w;
    q += f.x * f.x + f.y * f.y + f.z * f.z + f.w * f.w;
  }
  s = wred_sum(s);
  q = wred_sum(q);
  __shared__ float rs[4], rq[4];
  const int lane = threadIdx.x & 63, wid = threadIdx.x >> 6;
  if (lane == 0) { rs[wid] = s; rq[wid] = q; }
  __syncthreads();
  if (threadIdx.x == 0) {
    float S = rs[0] + rs[1] + rs[2] + rs[3];
    float Q = rq[0] + rq[1] + rq[2] + rq[3];
    float mean = S * (1.f / 65536.f);
    float var = Q * (1.f / 65536.f) - mean * mean;
    stats[2 * bg] = mean;
    stats[2 * bg + 1] = rsqrtf(var + 1e-5f);
  }
}

__global__ __launch_bounds__(256) void gn_apply_k(const float* __restrict__ x,
                                                  const float* __restrict__ stats,
                                                  const float* __restrict__ gs,
                                                  const float* __restrict__ gb,
                                                  ushort_t* __restrict__ h) {
  __shared__ ushort_t tile[32][33];
  const int bid = blockIdx.x;
  const int b = bid >> 11;
  const int r = bid & 2047;
  const int ct = r >> 7, nt = r & 127;
  const int c0 = ct << 5, n0 = nt << 5;
  const int tx = threadIdx.x & 31, ty = threadIdx.x >> 5;
#pragma unroll
  for (int i = 0; i < 4; ++i) {
    const int c = c0 + ty + i * 8;
    const float mean = stats[2 * (b * 32 + (c >> 4))];
    const float rstd = stats[2 * (b * 32 + (c >> 4)) + 1];
    const float xv = x[(((size_t)b * 512 + c) << 12) + n0 + tx];
    tile[ty + i * 8][tx] = f2bf((xv - mean) * rstd * gs[c] + gb[c]);
  }
  __syncthreads();
#pragma unroll
  for (int i = 0; i < 4; ++i) {
    const int n = n0 + ty + i * 8;
    h[(((size_t)b << 12) + n) * 512 + c0 + tx] = tile[tx][ty + i * 8];
  }
}

// fp32 -> bf16 convert with per-matrix scale (sc folded into wq)
struct Ptr4 { const float* src[4]; float wsc[4]; };
__global__ __launch_bounds__(256) void cvt_all_k(Ptr4 s, ushort_t* __restrict__ dst) {
  const int i = blockIdx.x * 256 + threadIdx.x;
  const int m = i >> 18;
  dst[i] = f2bf(s.src[m][i & 262143] * s.wsc[m]);
}

// ---------------- NT GEMM (128x128, 2-barrier): C[M,N] = A[M,K] * B[N,K]^T ----
// EPI 2: fp32 transposed out + resid + bias (final projection).
// EPI 3: QKV fused, z picks weight/bias/out; z==2 (V) writes transposed [C][N].
struct Ptr3 { const float* bias[3]; ushort_t* out[3]; float bs[3]; };

template <int BM, int BN, int BK, int EPI>
__global__ __launch_bounds__(256) void gemm_nt_k(
    const ushort_t* __restrict__ A, int lda, const ushort_t* __restrict__ Bm, int ldb,
    void* __restrict__ Cout, int ldc, const float* __restrict__ bias,
    const float* __restrict__ resid, float scale, int K,
    size_t azs, size_t bzs, size_t czs, Ptr3 p3) {
  constexpr int CPR = BK / 8;
  constexpr int WTM = BM / 2, WTN = BN / 2;
  constexpr int MI = WTM / 16, NI = WTN / 16;
  constexpr int AR = (BM * CPR) / 256;
  constexpr int BR = (BN * CPR) / 256;
  __shared__ ushort_t Als[BM * BK];
  __shared__ ushort_t Bls[BN * BK];
  const int tid = threadIdx.x;
  const int lane = tid & 63;
  const int wid = tid >> 6;
  const int quad = lane >> 4;
  const int r16 = lane & 15;
  const int wm = wid >> 1, wn = wid & 1;
  const int m0 = blockIdx.y * BM;
  const int n0 = blockIdx.x * BN;
  const int zb = blockIdx.z;

  A += azs * zb;
  Bm += bzs * zb;

  f32x4 acc[MI][NI] = {};

  for (int kt = 0; kt < K; kt += BK) {
#pragma unroll
    for (int r = 0; r < AR; ++r) {
      const int s = r * 256 + tid;
      const int row = s / CPR;
      const int q = (s % CPR) ^ fswz<CPR>(row);
      async16(&Als[s << 3], A + (size_t)(m0 + row) * lda + kt + (q << 3));
    }
#pragma unroll
    for (int r = 0; r < BR; ++r) {
      const int s = r * 256 + tid;
      const int row = s / CPR;
      const int q = (s % CPR) ^ fswz<CPR>(row);
      async16(&Bls[s << 3], Bm + (size_t)(n0 + row) * ldb + kt + (q << 3));
    }
    __syncthreads();
#pragma unroll
    for (int kf = 0; kf < BK / 32; ++kf) {
      bf16x8 af[MI], bfr[NI];
#pragma unroll
      for (int mi = 0; mi < MI; ++mi) {
        const int lr = wm * WTM + mi * 16 + r16;
        const int ch = kf * 4 + quad;
        af[mi] = *reinterpret_cast<const bf16x8*>(
            &Als[(lr * CPR + (ch ^ fswz<CPR>(lr))) << 3]);
      }
#pragma unroll
      for (int ni = 0; ni < NI; ++ni) {
        const int lr = wn * WTN + ni * 16 + r16;
        const int ch = kf * 4 + quad;
        bfr[ni] = *reinterpret_cast<const bf16x8*>(
            &Bls[(lr * CPR + (ch ^ fswz<CPR>(lr))) << 3]);
      }
#pragma unroll
      for (int mi = 0; mi < MI; ++mi)
#pragma unroll
        for (int ni = 0; ni < NI; ++ni)
          acc[mi][ni] = __builtin_amdgcn_mfma_f32_16x16x32_bf16(
              af[mi], bfr[ni], acc[mi][ni], 0, 0, 0);
    }
    __syncthreads();
  }

  const int mrow = m0 + wm * WTM;
  const int ncol = n0 + wn * WTN;
  if constexpr (EPI == 2) {  // final: fp32 transposed out + resid + bias
    float* C = (float*)Cout;
#pragma unroll
    for (int ni = 0; ni < NI; ++ni) {
      const int col = ncol + ni * 16 + r16;
      const float bvv = bias[col];
#pragma unroll
      for (int mi = 0; mi < MI; ++mi) {
        const int rowb = mrow + mi * 16 + quad * 4;
        const int bb = rowb >> 12;
        const int nl = rowb & 4095;
        const size_t base = (((size_t)bb * 512 + col) << 12) + nl;
        const float4 rv = *(const float4*)&resid[base];
        float4 ov;
        ov.x = rv.x + acc[mi][ni][0] + bvv;
        ov.y = rv.y + acc[mi][ni][1] + bvv;
        ov.z = rv.z + acc[mi][ni][2] + bvv;
        ov.w = rv.w + acc[mi][ni][3] + bvv;
        *(float4*)&C[base] = ov;
      }
    }
  } else if constexpr (EPI == 3) {  // QKV, z picks weight/bias/out; z==2 V^T
    const float* bz = p3.bias[zb];
    const float bsc = p3.bs[zb];
    ushort_t* O = p3.out[zb];
    if (zb < 2) {
#pragma unroll
      for (int ni = 0; ni < NI; ++ni) {
        const int col = ncol + ni * 16 + r16;
        const float bvv = bz[col] * bsc;
#pragma unroll
        for (int mi = 0; mi < MI; ++mi) {
          const int rowb = mrow + mi * 16 + quad * 4;
#pragma unroll
          for (int rr = 0; rr < 4; ++rr)
            O[(size_t)(rowb + rr) * 512 + col] = f2bf(acc[mi][ni][rr] + bvv);
        }
      }
    } else {
#pragma unroll
      for (int ni = 0; ni < NI; ++ni) {
        const int col = ncol + ni * 16 + r16;
        const float bvv = bz[col];
#pragma unroll
        for (int mi = 0; mi < MI; ++mi) {
          const int rowb = mrow + mi * 16 + quad * 4;
          const int bb = rowb >> 12;
          const int nn = rowb & 4095;
          ushort4 pk;
          pk.x = f2bf(acc[mi][ni][0] + bvv);
          pk.y = f2bf(acc[mi][ni][1] + bvv);
          pk.z = f2bf(acc[mi][ni][2] + bvv);
          pk.w = f2bf(acc[mi][ni][3] + bvv);
          *(ushort4*)&O[(((size_t)bb * 512 + col) << 12) + nn] = pk;
        }
      }
    }
  }
}

// ---- 4-wave ONE-barrier-per-K-tile GEMM (BK=32), 2 blocks/CU by design ----
// Round-4 winning schedule at half the block size: 256 threads, 2x2 waves,
// wave tiles sized so arch+acc fits 256 regs (no launch-bounds squeeze —
// round-6 lesson). Per tile: drain lgkm+vm, single barrier, stage all of
// tile t+1 (other buffer), then an unwalled ds_read+MFMA region the
// compiler pipelines. Co-resident block hides drains/prologue/epilogue.
// EPI 4: scores (128x256 tile) -> exp(acc) bf16 store.
// EPI 5: PV (128x128 tile) -> acc / l, l via ones-MFMA.
template <int BM, int BN, int EPI>
__global__ __launch_bounds__(256, 2) void gemm4_k(
    const ushort_t* __restrict__ A, int lda,
    const ushort_t* __restrict__ Bm, int ldb,
    void* __restrict__ Cout, int ldc, int K,
    size_t azs, size_t bzs, size_t czs) {
  constexpr int WTM = BM / 2, WTN = BN / 2;   // 2x2 waves
  constexpr int MI = WTM / 16, NI = WTN / 16;
  constexpr int MH = MI / 2;
  constexpr int ALD = BM / 64, BLD = BN / 64, TOT = ALD + BLD;
  constexpr int AHALF = BM * 32;              // ushorts per A buffer (BK=32)
  constexpr int HALF = (BM + BN) * 32;

  extern __shared__ ushort_t lds8[];
  const int tid = threadIdx.x;
  const int lane = tid & 63;
  const int quad = lane >> 4;
  const int r16 = lane & 15;
  const int wid = tid >> 6;
  const int wm = wid >> 1, wn = wid & 1;

  // XCD-clustered bijective block swizzle (HW: xcd = flat & 7)
  int bx, by, bz;
  if constexpr (EPI == 4) {  // grid 16x32x4 = 2048: 4x4 clusters per XCD
    const int flat = blockIdx.x + 16 * (blockIdx.y + 32 * blockIdx.z);
    const int xcd = flat & 7, s = flat >> 3;
    const int idx = s & 15, cid = (s >> 4) & 3;
    bz = s >> 6;
    const int cg = xcd + 8 * cid;            // cluster 0..31
    bx = (cg & 3) * 4 + (idx & 3);
    by = (cg >> 2) * 4 + (idx >> 2);
  } else {                   // grid 4x32x4 = 512: by-chunk of 4 per XCD
    const int flat = blockIdx.x + 4 * (blockIdx.y + 32 * blockIdx.z);
    const int xcd = flat & 7, s = flat >> 3;  // s in [0,64)
    bx = s & 3;
    by = xcd * 4 + ((s >> 2) & 3);
    bz = s >> 4;
  }
  const int m0 = by * BM, n0 = bx * BN, zb = bz;
  A += azs * zb;
  Bm += bzs * zb;
  const int NT = K >> 5;

  // per-thread stage sources + LDS dest offsets (proven CPR=4 chunk swizzle)
  const ushort_t* src[TOT];
  int dsto[TOT];
#pragma unroll
  for (int l = 0; l < TOT; ++l) {
    const bool isA = l < ALD;
    const int li = isA ? l : l - ALD;
    const int s = li * 256 + tid;
    const int row = s >> 2;                   // 4 chunks of 8 ushorts per row
    const int q = (s & 3) ^ ((row >> 2) & 3);
    src[l] = (isA ? A + (size_t)(m0 + row) * lda
                  : Bm + (size_t)(n0 + row) * ldb) + (q << 3);
    dsto[l] = (isA ? 0 : AHALF) + (s << 3);
  }

  f32x4 acc[MI][NI] = {};
  f32x4 acc_l[MI] = {};
  bf16x8 ones;
  {
    union { ushort_t u; __bf16 b; } o1; o1.u = 0x3F80;  // bf16 1.0
#pragma unroll
    for (int j = 0; j < 8; ++j) ones[j] = o1.b;
  }

  // prologue: stage tile 0 into buffer 0
#pragma unroll
  for (int l = 0; l < TOT; ++l) async16(lds8 + dsto[l], src[l]);

  for (int t = 0; t < NT; ++t) {
    const int nbuf = (t + 1) & 1;
    const ushort_t* Ab = lds8 + (t & 1) * HALF;
    const ushort_t* Bb = Ab + AHALF;
    // clamped source (dummy re-stage on last tile keeps the ledger uniform)
    const int koff = ((t + 1 < NT) ? t + 1 : NT - 1) << 5;

    // gate: my reads done (lgkm) and tile-t DMAs landed (vm; issued a full
    // tile ago). Barrier globalizes both.
    asm volatile("s_waitcnt vmcnt(0) lgkmcnt(0)" ::: "memory");
    __builtin_amdgcn_s_barrier();

    // stage the whole next tile (other buffer)
#pragma unroll
    for (int l = 0; l < TOT; ++l)
      async16(lds8 + nbuf * HALF + dsto[l], src[l] + koff);

    // unwalled read+MFMA region: full B, A in halves
    bf16x8 b_[NI], a_[MH];
#pragma unroll
    for (int j = 0; j < NI; ++j) {
      const int lr = wn * WTN + j * 16 + r16;
      const int cc = quad ^ ((lr >> 2) & 3);
      b_[j] = *reinterpret_cast<const bf16x8*>(&Bb[lr * 32 + cc * 8]);
    }
#pragma unroll
    for (int h = 0; h < 2; ++h) {
#pragma unroll
      for (int i = 0; i < MH; ++i) {
        const int lr = wm * WTM + (h * MH + i) * 16 + r16;
        const int cc = quad ^ ((lr >> 2) & 3);
        a_[i] = *reinterpret_cast<const bf16x8*>(&Ab[lr * 32 + cc * 8]);
      }
      __builtin_amdgcn_s_setprio(1);
#pragma unroll
      for (int i = 0; i < MH; ++i)
#pragma unroll
        for (int j = 0; j < NI; ++j)
          acc[h * MH + i][j] = __builtin_amdgcn_mfma_f32_16x16x32_bf16(
              a_[i], b_[j], acc[h * MH + i][j], 0, 0, 0);
      if constexpr (EPI == 5) {
#pragma unroll
        for (int i = 0; i < MH; ++i)
          acc_l[h * MH + i] = __builtin_amdgcn_mfma_f32_16x16x32_bf16(
              a_[i], ones, acc_l[h * MH + i], 0, 0, 0);
      }
      __builtin_amdgcn_s_setprio(0);
    }
  }
  // drain trailing dummy-stage DMAs before block retires
  asm volatile("s_waitcnt vmcnt(0)" ::: "memory");

  const int mrow = m0 + wm * WTM;
  const int ncol = n0 + wn * WTN;
  if constexpr (EPI == 4) {  // scores: exp + bf16 store, no reduce
    ushort_t* C = (ushort_t*)Cout + czs * zb;
#pragma unroll
    for (int mi = 0; mi < MI; ++mi) {
#pragma unroll
      for (int rr = 0; rr < 4; ++rr) {
        const int row = mrow + mi * 16 + quad * 4 + rr;
#pragma unroll
        for (int ni = 0; ni < NI; ++ni) {
          const int col = ncol + ni * 16 + r16;
          C[(size_t)row * ldc + col] = f2bf(__expf(acc[mi][ni][rr]));
        }
      }
    }
  } else {  // EPI == 5: PV, divide by in-register row sum, bf16 out
    ushort_t* C = (ushort_t*)Cout + czs * zb;
#pragma unroll
    for (int mi = 0; mi < MI; ++mi) {
#pragma unroll
      for (int rr = 0; rr < 4; ++rr) {
        const int row = mrow + mi * 16 + quad * 4 + rr;
        const float inv = 1.f / acc_l[mi][rr];
#pragma unroll
        for (int ni = 0; ni < NI; ++ni) {
          const int col = ncol + ni * 16 + r16;
          C[(size_t)row * ldc + col] = f2bf(acc[mi][ni][rr] * inv);
        }
      }
    }
  }
}

extern "C" void kernel_launch(void* const* d_in, const int* in_sizes, int n_in,
                              void* d_out, int out_size, void* d_ws, size_t ws_size,
                              hipStream_t stream) {
  const float* x  = (const float*)d_in[0];
  const float* gs = (const float*)d_in[1];
  const float* gb = (const float*)d_in[2];
  const float* wq = (const float*)d_in[3];
  const float* bq = (const float*)d_in[4];
  const float* wk = (const float*)d_in[5];
  const float* bk = (const float*)d_in[6];
  const float* wv = (const float*)d_in[7];
  const float* bv = (const float*)d_in[8];
  const float* wo = (const float*)d_in[9];
  const float* bo = (const float*)d_in[10];
  float* out = (float*)d_out;

  const size_t HNC = (size_t)4 * 4096 * 512;
  char* w = (char*)d_ws;
  float* stats  = (float*)w;    w += 4096;
  ushort_t* wb  = (ushort_t*)w; w += (size_t)4 * 262144 * 2;
  ushort_t* h   = (ushort_t*)w; w += HNC * 2;  // GN out; reused as O
  ushort_t* q   = (ushort_t*)w; w += HNC * 2;
  ushort_t* kk  = (ushort_t*)w; w += HNC * 2;
  ushort_t* vt  = (ushort_t*)w; w += HNC * 2;  // V transposed [B,C,N]
  ushort_t* Se  = (ushort_t*)w; w += (size_t)4 * 4096 * 4096 * 2;  // exp(S) bf16

  const float sc = 0.044194173824159216f;  // 512^-0.5, folded into wq/bq

  static bool attr_done = false;
  if (!attr_done) {
    (void)hipFuncSetAttribute((const void*)gemm4_k<128, 256, 4>,
                              hipFuncAttributeMaxDynamicSharedMemorySize, 49152);
    (void)hipFuncSetAttribute((const void*)gemm4_k<128, 128, 5>,
                              hipFuncAttributeMaxDynamicSharedMemorySize, 32768);
    attr_done = true;
  }

  gn_stats_k<<<128, 256, 0, stream>>>(x, stats);
  gn_apply_k<<<8192, 256, 0, stream>>>(x, stats, gs, gb, h);
  Ptr4 wsrc;
  wsrc.src[0] = wq; wsrc.src[1] = wk; wsrc.src[2] = wv; wsrc.src[3] = wo;
  wsrc.wsc[0] = sc; wsrc.wsc[1] = 1.f; wsrc.wsc[2] = 1.f; wsrc.wsc[3] = 1.f;
  cvt_all_k<<<4096, 256, 0, stream>>>(wsrc, wb);

  Ptr3 qkv;
  qkv.bias[0] = bq; qkv.bias[1] = bk; qkv.bias[2] = bv;
  qkv.out[0] = q; qkv.out[1] = kk; qkv.out[2] = vt;
  qkv.bs[0] = sc; qkv.bs[1] = 1.f; qkv.bs[2] = 1.f;
  gemm_nt_k<128, 128, 32, 3><<<dim3(4, 128, 3), 256, 0, stream>>>(
      h, 512, wb, 512, nullptr, 0, nullptr, nullptr, 1.f, 512,
      0, 262144, 0, qkv);

  // Se[z] = exp(q k^T) bf16 — 128x256 tiles, 2 blocks/CU
  gemm4_k<128, 256, 4><<<dim3(16, 32, 4), 256, 49152, stream>>>(
      q, 512, kk, 512, Se, 4096, 512,
      (size_t)4096 * 512, (size_t)4096 * 512, (size_t)4096 * 4096);
  // O[z] = (Se V) / l — 128x128 tiles, 2-3 blocks/CU, l via ones-MFMA
  gemm4_k<128, 128, 5><<<dim3(4, 32, 4), 256, 32768, stream>>>(
      Se, 4096, vt, 4096, h, 512, 4096,
      (size_t)4096 * 4096, (size_t)512 * 4096, (size_t)4096 * 512);

  // out = x + O @ wo^T + bo, transposed back to [B,C,H,W]
  Ptr3 e0{};
  gemm_nt_k<128, 128, 32, 2><<<dim3(4, 128, 1), 256, 0, stream>>>(
      h, 512, wb + (size_t)3 * 262144, 512, out, 512, bo, x, 1.f, 512,
      0, 0, 0, e0);
}

// Round 9
// 336.435 us; speedup vs baseline: 2.7801x; 1.1459x over previous
//
#include <hip/hip_runtime.h>
#include <cstdint>
#include <cstddef>

typedef unsigned short ushort_t;
typedef __attribute__((ext_vector_type(8))) __bf16 bf16x8;
typedef __attribute__((ext_vector_type(4))) float f32x4;

#define DEVINL __device__ __forceinline__

DEVINL ushort_t f2bf(float f) {
  union { __bf16 b; ushort_t u; } v;
  v.b = (__bf16)f;
  return v.u;
}
DEVINL float bf2f(ushort_t u) {
  union { unsigned u; float f; } v; v.u = ((unsigned)u) << 16;
  return v.f;
}

DEVINL float wred_sum(float x) {
#pragma unroll
  for (int o = 32; o > 0; o >>= 1) x += __shfl_xor(x, o, 64);
  return x;
}

// async global->LDS, 16B per lane (global_load_lds_dwordx4)
DEVINL void async16(ushort_t* lds, const ushort_t* g) {
  __builtin_amdgcn_global_load_lds(
      (__attribute__((address_space(1))) const unsigned int*)g,
      (__attribute__((address_space(3))) unsigned int*)lds, 16, 0, 0);
}

template <int CPR>
DEVINL int fswz(int r) {
  if constexpr (CPR == 4) return (r >> 2) & 3;
  else return r & 7;  // CPR==8
}

// ---------------- GroupNorm ----------------
// stats split 4-ways per (b,g): raw S/Q sums via f32 atomics (512 blocks).
__global__ __launch_bounds__(256) void gn_stats_k(const float* __restrict__ x,
                                                  float* __restrict__ stats) {
  const int bg = blockIdx.x >> 2, sl = blockIdx.x & 3;
  const float4* base = (const float4*)(x + ((size_t)bg << 16) + (sl << 14));
  float s = 0.f, q = 0.f;
  for (int i = threadIdx.x; i < 4096; i += 256) {
    float4 f = base[i];
    s += f.x + f.y + f.z + f.w;
    q += f.x * f.x + f.y * f.y + f.z * f.z + f.w * f.w;
  }
  s = wred_sum(s);
  q = wred_sum(q);
  __shared__ float rs[4], rq[4];
  const int lane = threadIdx.x & 63, wid = threadIdx.x >> 6;
  if (lane == 0) { rs[wid] = s; rq[wid] = q; }
  __syncthreads();
  if (threadIdx.x == 0) {
    atomicAdd(&stats[2 * bg], rs[0] + rs[1] + rs[2] + rs[3]);
    atomicAdd(&stats[2 * bg + 1], rq[0] + rq[1] + rq[2] + rq[3]);
  }
}

__global__ __launch_bounds__(256) void gn_apply_k(const float* __restrict__ x,
                                                  const float* __restrict__ stats,
                                                  const float* __restrict__ gs,
                                                  const float* __restrict__ gb,
                                                  ushort_t* __restrict__ h) {
  __shared__ ushort_t tile[32][33];
  const int bid = blockIdx.x;
  const int b = bid >> 11;
  const int r = bid & 2047;
  const int ct = r >> 7, nt = r & 127;
  const int c0 = ct << 5, n0 = nt << 5;
  const int tx = threadIdx.x & 31, ty = threadIdx.x >> 5;
#pragma unroll
  for (int i = 0; i < 4; ++i) {
    const int c = c0 + ty + i * 8;
    const int gidx = b * 32 + (c >> 4);
    const float mean = stats[2 * gidx] * (1.f / 65536.f);
    const float var = stats[2 * gidx + 1] * (1.f / 65536.f) - mean * mean;
    const float rstd = rsqrtf(var + 1e-5f);
    const float xv = x[(((size_t)b * 512 + c) << 12) + n0 + tx];
    tile[ty + i * 8][tx] = f2bf((xv - mean) * rstd * gs[c] + gb[c]);
  }
  __syncthreads();
#pragma unroll
  for (int i = 0; i < 4; ++i) {
    const int n = n0 + ty + i * 8;
    h[(((size_t)b << 12) + n) * 512 + c0 + tx] = tile[tx][ty + i * 8];
  }
}

// fp32 -> bf16 convert with per-matrix scale (sc folded into wq)
struct Ptr4 { const float* src[4]; float wsc[4]; };
__global__ __launch_bounds__(256) void cvt_all_k(Ptr4 s, ushort_t* __restrict__ dst) {
  const int i = blockIdx.x * 256 + threadIdx.x;
  const int m = i >> 18;
  dst[i] = f2bf(s.src[m][i & 262143] * s.wsc[m]);
}

struct Ptr3 { const float* bias[3]; ushort_t* out[3]; float bs[3]; };

// ------- 8-wave, ONE-barrier-per-K-tile pipelined NT GEMM (round-4) -------
// BK=64, double-buffered LDS. Per tile: drain lgkm+vm, single barrier,
// stage the whole next tile (into the other buffer), then an UNWALLED
// region of ds_read_b128 + MFMA that the compiler pipelines with partial
// lgkmcnt waits. No intra-tile barriers. Stage-after-barrier prevents DMA
// landing in a buffer a slow wave still reads.
// EPI 2: fp32 transposed out + resid + bias (final projection).
// EPI 3: QKV fused, z picks weight/bias/out; z==2 (V) writes transposed.
// EPI 4: scores -> exp(acc) bf16 store (no reduce, no atomics).
// EPI 5: PV -> acc / l, l computed IN-KERNEL via MFMA with all-ones B.
template <int BM, int BN, int WGM, int WGN, int EPI>
__global__ __launch_bounds__(512, 2) void gemm8l_k(
    const ushort_t* __restrict__ A, int lda,
    const ushort_t* __restrict__ Bm, int ldb,
    void* __restrict__ Cout, int ldc, int K,
    size_t azs, size_t bzs, size_t czs,
    const float* __restrict__ bias, const float* __restrict__ resid, Ptr3 p3) {
  constexpr int WTM = BM / WGM, WTN = BN / WGN;
  constexpr int MI = WTM / 16, NI = WTN / 16;
  constexpr int MH = MI / 2;
  constexpr int ALD = BM / 64, BLD = BN / 64, TOT = ALD + BLD;
  constexpr int AHALF = BM * 64;      // ushorts per A buffer
  constexpr int HALF = (BM + BN) * 64;

  extern __shared__ ushort_t lds8[];
  const int tid = threadIdx.x;
  const int lane = tid & 63;
  const int quad = lane >> 4;
  const int r16 = lane & 15;
  const int wid = tid >> 6;
  const int wm = wid / WGN, wn = wid % WGN;

  // XCD-clustered block swizzle for attention shapes; identity elsewhere
  int bx, by, bz;
  if constexpr (EPI == 4) {  // grid 16x16x4: 4x4 tile-chunks per XCD
    const int flat = blockIdx.x + 16 * (blockIdx.y + 16 * blockIdx.z);
    const int xcd = flat & 7, s = flat >> 3;
    const int w = s & 31, half = w >> 4, idx = w & 15;
    bx = (xcd & 3) * 4 + (idx & 3);
    by = ((xcd >> 2) + 2 * half) * 4 + (idx >> 2);
    bz = s >> 5;
  } else if constexpr (EPI == 5) {  // grid 4x16x4: x-siblings per XCD
    const int flat = blockIdx.x + 4 * (blockIdx.y + 16 * blockIdx.z);
    const int xcd = flat & 7, s = flat >> 3;
    bx = s & 3;
    const int yz = xcd + (s >> 2) * 8;
    by = yz & 15; bz = yz >> 4;
  } else {
    bx = blockIdx.x; by = blockIdx.y; bz = blockIdx.z;
  }
  const int m0 = by * BM, n0 = bx * BN, zb = bz;
  A += azs * zb;
  Bm += bzs * zb;
  const int NT = K >> 6;

  // per-thread stage sources + LDS dest offsets (proven CPR=8 chunk swizzle)
  const ushort_t* src[TOT];
  int dsto[TOT];
#pragma unroll
  for (int l = 0; l < TOT; ++l) {
    const bool isA = l < ALD;
    const int li = isA ? l : l - ALD;
    const int s = li * 512 + tid;
    const int row = s >> 3;
    const int q = (s & 7) ^ (row & 7);
    src[l] = (isA ? A + (size_t)(m0 + row) * lda
                  : Bm + (size_t)(n0 + row) * ldb) + (q << 3);
    dsto[l] = (isA ? 0 : AHALF) + (s << 3);
  }

  f32x4 acc[MI][NI] = {};
  f32x4 acc_l[MI] = {};
  bf16x8 ones;
  {
    union { ushort_t u; __bf16 b; } o1; o1.u = 0x3F80;  // bf16 1.0
#pragma unroll
    for (int j = 0; j < 8; ++j) ones[j] = o1.b;
  }

  // prologue: stage tile 0 into buffer 0
#pragma unroll
  for (int l = 0; l < TOT; ++l) async16(lds8 + dsto[l], src[l]);

  for (int t = 0; t < NT; ++t) {
    const int nbuf = (t + 1) & 1;
    const ushort_t* Ab = lds8 + (t & 1) * HALF;
    const ushort_t* Bb = Ab + AHALF;
    // clamped source (dummy re-stage on last tile keeps the ledger uniform)
    const int koff = ((t + 1 < NT) ? t + 1 : NT - 1) << 6;

    // gate: my reads are physically done (lgkm) and my tile-t DMAs landed
    // (vm; issued a full tile ago, so cheap). Barrier makes it global.
    asm volatile("s_waitcnt vmcnt(0) lgkmcnt(0)" ::: "memory");
    __builtin_amdgcn_s_barrier();

    // stage the whole next tile (other buffer) — after the barrier, so no
    // DMA can land in a buffer a slower wave still reads.
#pragma unroll
    for (int l = 0; l < TOT; ++l)
      async16(lds8 + nbuf * HALF + dsto[l], src[l] + koff);

    // unwalled read+MFMA region: full B, A in halves
    bf16x8 bfr[NI][2], af[MH][2];
#pragma unroll
    for (int ni = 0; ni < NI; ++ni)
#pragma unroll
      for (int kf = 0; kf < 2; ++kf) {
        const int lr = wn * WTN + ni * 16 + r16;
        const int cc = (kf * 4 + quad) ^ (lr & 7);
        bfr[ni][kf] = *reinterpret_cast<const bf16x8*>(&Bb[lr * 64 + cc * 8]);
      }
#pragma unroll
    for (int h = 0; h < 2; ++h) {
#pragma unroll
      for (int i = 0; i < MH; ++i)
#pragma unroll
        for (int kf = 0; kf < 2; ++kf) {
          const int lr = wm * WTM + (h * MH + i) * 16 + r16;
          const int cc = (kf * 4 + quad) ^ (lr & 7);
          af[i][kf] = *reinterpret_cast<const bf16x8*>(&Ab[lr * 64 + cc * 8]);
        }
      __builtin_amdgcn_s_setprio(1);
#pragma unroll
      for (int i = 0; i < MH; ++i)
#pragma unroll
        for (int ni = 0; ni < NI; ++ni)
#pragma unroll
          for (int kf = 0; kf < 2; ++kf)
            acc[h * MH + i][ni] = __builtin_amdgcn_mfma_f32_16x16x32_bf16(
                af[i][kf], bfr[ni][kf], acc[h * MH + i][ni], 0, 0, 0);
      if constexpr (EPI == 5) {
#pragma unroll
        for (int i = 0; i < MH; ++i)
#pragma unroll
          for (int kf = 0; kf < 2; ++kf)
            acc_l[h * MH + i] = __builtin_amdgcn_mfma_f32_16x16x32_bf16(
                af[i][kf], ones, acc_l[h * MH + i], 0, 0, 0);
      }
      __builtin_amdgcn_s_setprio(0);
    }
  }
  // drain trailing dummy-stage DMAs so they can't land in a successor
  // block's LDS after this block retires.
  asm volatile("s_waitcnt vmcnt(0)" ::: "memory");

  const int mrow = m0 + wm * WTM;
  const int ncol = n0 + wn * WTN;
  if constexpr (EPI == 4) {  // scores: exp + bf16 store, no reduce
    ushort_t* C = (ushort_t*)Cout + czs * zb;
#pragma unroll
    for (int mi = 0; mi < MI; ++mi) {
#pragma unroll
      for (int rr = 0; rr < 4; ++rr) {
        const int row = mrow + mi * 16 + quad * 4 + rr;
#pragma unroll
        for (int ni = 0; ni < NI; ++ni) {
          const int col = ncol + ni * 16 + r16;
          C[(size_t)row * ldc + col] = f2bf(__expf(acc[mi][ni][rr]));
        }
      }
    }
  } else if constexpr (EPI == 5) {  // PV: divide by in-register row sum
    ushort_t* C = (ushort_t*)Cout + czs * zb;
#pragma unroll
    for (int mi = 0; mi < MI; ++mi) {
#pragma unroll
      for (int rr = 0; rr < 4; ++rr) {
        const int row = mrow + mi * 16 + quad * 4 + rr;
        const float inv = 1.f / acc_l[mi][rr];
#pragma unroll
        for (int ni = 0; ni < NI; ++ni) {
          const int col = ncol + ni * 16 + r16;
          C[(size_t)row * ldc + col] = f2bf(acc[mi][ni][rr] * inv);
        }
      }
    }
  } else if constexpr (EPI == 2) {  // final: fp32 transposed out + resid
    float* C = (float*)Cout;
#pragma unroll
    for (int ni = 0; ni < NI; ++ni) {
      const int col = ncol + ni * 16 + r16;
      const float bvv = bias[col];
#pragma unroll
      for (int mi = 0; mi < MI; ++mi) {
        const int rowb = mrow + mi * 16 + quad * 4;
        const int bb = rowb >> 12;
        const int nl = rowb & 4095;
        const size_t base = (((size_t)bb * 512 + col) << 12) + nl;
        const float4 rv = *(const float4*)&resid[base];
        float4 ov;
        ov.x = rv.x + acc[mi][ni][0] + bvv;
        ov.y = rv.y + acc[mi][ni][1] + bvv;
        ov.z = rv.z + acc[mi][ni][2] + bvv;
        ov.w = rv.w + acc[mi][ni][3] + bvv;
        *(float4*)&C[base] = ov;
      }
    }
  } else {  // EPI == 3: QKV, z picks weight/bias/out; z==2 V^T
    const float* bz = p3.bias[zb];
    const float bsc = p3.bs[zb];
    ushort_t* O = p3.out[zb];
    if (zb < 2) {
#pragma unroll
      for (int ni = 0; ni < NI; ++ni) {
        const int col = ncol + ni * 16 + r16;
        const float bvv = bz[col] * bsc;
#pragma unroll
        for (int mi = 0; mi < MI; ++mi) {
          const int rowb = mrow + mi * 16 + quad * 4;
#pragma unroll
          for (int rr = 0; rr < 4; ++rr)
            O[(size_t)(rowb + rr) * 512 + col] = f2bf(acc[mi][ni][rr] + bvv);
        }
      }
    } else {
#pragma unroll
      for (int ni = 0; ni < NI; ++ni) {
        const int col = ncol + ni * 16 + r16;
        const float bvv = bz[col];
#pragma unroll
        for (int mi = 0; mi < MI; ++mi) {
          const int rowb = mrow + mi * 16 + quad * 4;
          const int bb = rowb >> 12;
          const int nn = rowb & 4095;
          ushort4 pk;
          pk.x = f2bf(acc[mi][ni][0] + bvv);
          pk.y = f2bf(acc[mi][ni][1] + bvv);
          pk.z = f2bf(acc[mi][ni][2] + bvv);
          pk.w = f2bf(acc[mi][ni][3] + bvv);
          *(ushort4*)&O[(((size_t)bb * 512 + col) << 12) + nn] = pk;
        }
      }
    }
  }
}

extern "C" void kernel_launch(void* const* d_in, const int* in_sizes, int n_in,
                              void* d_out, int out_size, void* d_ws, size_t ws_size,
                              hipStream_t stream) {
  const float* x  = (const float*)d_in[0];
  const float* gs = (const float*)d_in[1];
  const float* gb = (const float*)d_in[2];
  const float* wq = (const float*)d_in[3];
  const float* bq = (const float*)d_in[4];
  const float* wk = (const float*)d_in[5];
  const float* bk = (const float*)d_in[6];
  const float* wv = (const float*)d_in[7];
  const float* bv = (const float*)d_in[8];
  const float* wo = (const float*)d_in[9];
  const float* bo = (const float*)d_in[10];
  float* out = (float*)d_out;

  const size_t HNC = (size_t)4 * 4096 * 512;
  char* w = (char*)d_ws;
  float* stats  = (float*)w;    w += 4096;
  ushort_t* wb  = (ushort_t*)w; w += (size_t)4 * 262144 * 2;
  ushort_t* h   = (ushort_t*)w; w += HNC * 2;  // GN out; reused as O
  ushort_t* q   = (ushort_t*)w; w += HNC * 2;
  ushort_t* kk  = (ushort_t*)w; w += HNC * 2;
  ushort_t* vt  = (ushort_t*)w; w += HNC * 2;  // V transposed [B,C,N]
  ushort_t* Se  = (ushort_t*)w; w += (size_t)4 * 4096 * 4096 * 2;  // exp(S) bf16

  const float sc = 0.044194173824159216f;  // 512^-0.5, folded into wq/bq

  static bool attr_done = false;
  if (!attr_done) {
    (void)hipFuncSetAttribute((const void*)gemm8l_k<256, 256, 2, 4, 4>,
                              hipFuncAttributeMaxDynamicSharedMemorySize, 131072);
    (void)hipFuncSetAttribute((const void*)gemm8l_k<256, 128, 4, 2, 5>,
                              hipFuncAttributeMaxDynamicSharedMemorySize, 98304);
    (void)hipFuncSetAttribute((const void*)gemm8l_k<256, 128, 4, 2, 3>,
                              hipFuncAttributeMaxDynamicSharedMemorySize, 98304);
    (void)hipFuncSetAttribute((const void*)gemm8l_k<256, 128, 4, 2, 2>,
                              hipFuncAttributeMaxDynamicSharedMemorySize, 98304);
    attr_done = true;
  }

  hipMemsetAsync(stats, 0, 128 * 2 * sizeof(float), stream);
  gn_stats_k<<<512, 256, 0, stream>>>(x, stats);
  gn_apply_k<<<8192, 256, 0, stream>>>(x, stats, gs, gb, h);
  Ptr4 wsrc;
  wsrc.src[0] = wq; wsrc.src[1] = wk; wsrc.src[2] = wv; wsrc.src[3] = wo;
  wsrc.wsc[0] = sc; wsrc.wsc[1] = 1.f; wsrc.wsc[2] = 1.f; wsrc.wsc[3] = 1.f;
  cvt_all_k<<<4096, 256, 0, stream>>>(wsrc, wb);

  Ptr3 qkv;
  qkv.bias[0] = bq; qkv.bias[1] = bk; qkv.bias[2] = bv;
  qkv.out[0] = q; qkv.out[1] = kk; qkv.out[2] = vt;
  qkv.bs[0] = sc; qkv.bs[1] = 1.f; qkv.bs[2] = 1.f;
  Ptr3 e0{};

  // QKV on the one-barrier pipeline: 256x128 tiles, grid (4,64,3)
  gemm8l_k<256, 128, 4, 2, 3><<<dim3(4, 64, 3), 512, 98304, stream>>>(
      h, 512, wb, 512, nullptr, 512, 512,
      0, 262144, 0, nullptr, nullptr, qkv);

  // Se[z] = exp(q k^T) bf16 (one-barrier pipeline, no reduce/atomics)
  gemm8l_k<256, 256, 2, 4, 4><<<dim3(16, 16, 4), 512, 131072, stream>>>(
      q, 512, kk, 512, Se, 4096, 512,
      (size_t)4096 * 512, (size_t)4096 * 512, (size_t)4096 * 4096,
      nullptr, nullptr, e0);
  // O[z] = (Se V) / l, l computed in-kernel via ones-MFMA
  gemm8l_k<256, 128, 4, 2, 5><<<dim3(4, 16, 4), 512, 98304, stream>>>(
      Se, 4096, vt, 4096, h, 512, 4096,
      (size_t)4096 * 4096, (size_t)512 * 4096, (size_t)4096 * 512,
      nullptr, nullptr, e0);

  // out = x + O @ wo^T + bo (one-barrier pipeline), transposed to [B,C,H,W]
  gemm8l_k<256, 128, 4, 2, 2><<<dim3(4, 64, 1), 512, 98304, stream>>>(
      h, 512, wb + (size_t)3 * 262144, 512, out, 512, 512,
      0, 0, 0, bo, x, e0);
}